// Round 1
// baseline (783.320 us; speedup 1.0000x reference)
//
#include <hip/hip_runtime.h>
#include <hip/hip_bf16.h>

#define HH 512
#define WW 512
#define NPIX (HH * WW)
#define KTOP 64
#define NBINS 4096
#define CAP 2048

static constexpr unsigned MINB = 0x3DCCCCCDu; // bits of 0.1f

__constant__ int KPT_A[19] = {1,1,2,3,5,6,1,8,9,1,11,12,1,0,14,0,15,2,5};
__constant__ int KPT_B[19] = {2,5,3,4,6,7,8,9,10,11,12,13,0,14,16,15,17,16,17};
__constant__ int PAF_X[19] = {12,20,14,16,22,24,0,2,4,6,8,10,28,30,34,32,36,18,26};
__constant__ int PAF_Y[19] = {13,21,15,17,23,25,1,3,5,7,9,11,29,31,35,33,37,19,27};

__global__ __launch_bounds__(1024) void peaks_kernel(
    const float* __restrict__ hm_all,
    float* __restrict__ coords, float* __restrict__ ss, float* __restrict__ ks)
{
    const int map = blockIdx.x;            // b*19 + c
    const float* hm = hm_all + (size_t)map * NPIX;
    const int tid = threadIdx.x;

    __shared__ unsigned hist[NBINS];
    __shared__ unsigned candBits[CAP];
    __shared__ unsigned candIdx[CAP];
    __shared__ unsigned chunkSum[256];
    __shared__ unsigned s_cnt;
    __shared__ unsigned s_thrBits;
    __shared__ int sx[KTOP], sy[KTOP], svalid[KTOP];
    __shared__ float sv[KTOP];
    __shared__ int ox[KTOP], oyv[KTOP], oval[KTOP];
    __shared__ float osc[KTOP];

    for (int i = tid; i < NBINS; i += blockDim.x) hist[i] = 0u;
    if (tid == 0) s_cnt = 0u;
    __syncthreads();

    auto tval = [&](int y, int x) -> float {
        if ((unsigned)x >= (unsigned)WW || (unsigned)y >= (unsigned)HH) return 0.0f;
        float v = hm[y * WW + x];
        return v < 0.1f ? 0.0f : v;
    };

    // Pass 1: histogram of peak values (bit-bins, monotone in value)
    for (int p = tid; p < NPIX; p += blockDim.x) {
        float v = hm[p];
        if (v < 0.1f) continue;
        int y = p >> 9, x = p & 511;
        if (v > tval(y, x + 1) && v > tval(y, x - 1) &&
            v > tval(y + 1, x) && v > tval(y - 1, x)) {
            unsigned b = (__float_as_uint(v) - MINB) >> 13;
            if (b >= NBINS) b = NBINS - 1;
            atomicAdd(&hist[b], 1u);
        }
    }
    __syncthreads();

    if (tid < 256) {
        unsigned s = 0;
        for (int k = 0; k < 16; k++) s += hist[tid * 16 + k];
        chunkSum[tid] = s;
    }
    __syncthreads();
    if (tid == 0) {
        unsigned total = 0;
        for (int k = 0; k < 256; k++) total += chunkSum[k];
        if (total < (unsigned)KTOP) {
            s_thrBits = MINB;   // collect every peak
        } else {
            unsigned acc = 0; int c = 255;
            for (; c >= 0; c--) {
                if (acc + chunkSum[c] >= (unsigned)KTOP) break;
                acc += chunkSum[c];
            }
            int b = c * 16 + 15;
            unsigned acc2 = acc;
            for (; b >= c * 16; b--) {
                if (acc2 + hist[b] >= (unsigned)KTOP) break;
                acc2 += hist[b];
            }
            s_thrBits = MINB + ((unsigned)b << 13);
        }
    }
    __syncthreads();
    const unsigned thrBits = s_thrBits;

    // Pass 2: collect candidates >= threshold bin
    for (int p = tid; p < NPIX; p += blockDim.x) {
        float v = hm[p];
        if (v < 0.1f) continue;
        if (__float_as_uint(v) < thrBits) continue;
        int y = p >> 9, x = p & 511;
        if (v > tval(y, x + 1) && v > tval(y, x - 1) &&
            v > tval(y + 1, x) && v > tval(y - 1, x)) {
            unsigned pos = atomicAdd(&s_cnt, 1u);
            if (pos < CAP) { candBits[pos] = __float_as_uint(v); candIdx[pos] = (unsigned)p; }
        }
    }
    __syncthreads();
    int n = (int)(s_cnt < (unsigned)CAP ? s_cnt : (unsigned)CAP);

    // Exact rank by (value desc, flat idx asc)  == jax.lax.top_k order
    for (int i = tid; i < n; i += blockDim.x) {
        unsigned bi = candBits[i], ii = candIdx[i];
        int rank = 0;
        for (int j = 0; j < n; j++) {
            unsigned bj = candBits[j];
            rank += (int)((bj > bi) || (bj == bi && candIdx[j] < ii));
        }
        if (rank < KTOP) {
            sx[rank] = (int)(ii & 511u);
            sy[rank] = (int)(ii >> 9);
            sv[rank] = __uint_as_float(bi);
            svalid[rank] = 1;
        }
    }
    __syncthreads();

    // Filler path (fewer than 64 peaks): top_k pads with -inf entries at the
    // smallest non-peak flat indices; score = thresholded hm there; valid=0.
    if (n < KTOP && tid == 0) {
        int cnt = n;
        for (int p = 0; p < NPIX && cnt < KTOP; p++) {
            float v = hm[p];
            float tv = v < 0.1f ? 0.0f : v;
            int y = p >> 9, x = p & 511;
            bool pk = (tv > tval(y, x + 1)) && (tv > tval(y, x - 1)) &&
                      (tv > tval(y + 1, x)) && (tv > tval(y - 1, x));
            if (!pk) { sx[cnt] = x; sy[cnt] = y; sv[cnt] = tv; svalid[cnt] = 0; cnt++; }
        }
    }
    __syncthreads();

    // Stable sort by (x asc, rank asc); invalid keyed at W+1 = 513
    if (tid < KTOP) {
        int xk = svalid[tid] ? sx[tid] : (WW + 1);
        int fpos = 0;
        for (int t = 0; t < KTOP; t++) {
            int xkt = svalid[t] ? sx[t] : (WW + 1);
            fpos += (int)((xkt < xk) || (xkt == xk && t < tid));
        }
        ox[fpos] = sx[tid]; oyv[fpos] = sy[tid]; osc[fpos] = sv[tid]; oval[fpos] = svalid[tid];
    }
    __syncthreads();

    // Greedy sequential NMS on one 64-lane wave
    if (tid < KTOP) {
        int x = ox[tid], y = oyv[tid];
        float sc = osc[tid];
        int valid = oval[tid];
        int keep = valid;
        for (int i = 0; i < KTOP; i++) {
            int ki = __shfl(keep, i);
            int xi = __shfl(x, i);
            int yi = __shfl(y, i);
            if (ki && tid > i) {
                int ddx = x - xi, ddy = y - yi;
                if (ddx * ddx + ddy * ddy < 36) keep = 0;
            }
        }
        size_t base = (size_t)map * KTOP + tid;
        coords[base * 2 + 0] = 2.0f * (float)x;
        coords[base * 2 + 1] = 2.0f * (float)y;
        ss[base] = sc;
        ks[base] = keep ? 1.0f : 0.0f;
    }
}

__global__ __launch_bounds__(256) void limbs_kernel(
    const float* __restrict__ paf_all,
    const float* __restrict__ coords, const float* __restrict__ ss, const float* __restrict__ ks,
    float* __restrict__ conn, float* __restrict__ cvalid)
{
    const int blk = blockIdx.x;
    const int q = blk & 15;
    const int bl = blk >> 4;              // b*19 + l
    const int b = bl / 19, l = bl % 19;
    const int tid = threadIdx.x;

    __shared__ float axs[64], ays[64], sas[64];
    __shared__ float bxs[64], bys[64], sbs[64];
    __shared__ int kas[64], kbs[64];

    const int cA = KPT_A[l], cB = KPT_B[l];
    if (tid < 64) {
        size_t ia = (size_t)(b * 19 + cA) * 64 + tid;
        axs[tid] = coords[ia * 2]     * 0.5f;
        ays[tid] = coords[ia * 2 + 1] * 0.5f;
        sas[tid] = ss[ia];
        kas[tid] = ks[ia] > 0.5f;
    } else if (tid < 128) {
        int t = tid - 64;
        size_t ib = (size_t)(b * 19 + cB) * 64 + t;
        bxs[t] = coords[ib * 2]     * 0.5f;
        bys[t] = coords[ib * 2 + 1] * 0.5f;
        sbs[t] = ss[ib];
        kbs[t] = ks[ib] > 0.5f;
    }
    __syncthreads();

    const float* __restrict__ pafx = paf_all + ((size_t)b * 38 + PAF_X[l]) * NPIX;
    const float* __restrict__ pafy = paf_all + ((size_t)b * 38 + PAF_Y[l]) * NPIX;

    const int pair = q * 256 + tid;
    const int i = pair >> 6, j = pair & 63;

    float ax = axs[i], ay = ays[i];
    float bx = bxs[j], by = bys[j];
    float dx = bx - ax, dy = by - ay;
    float norm = sqrtf(__fadd_rn(__fmul_rn(dx, dx), __fmul_rn(dy, dy)));
    float safe = fmaxf(norm, 1e-6f);
    float ux = dx / safe, uy = dy / safe;

    int npass = 0;
    float ssum = 0.0f;
#pragma unroll
    for (int k = 0; k < 10; k++) {
        float tk = (float)k / 9.0f;
        float pxf = __fadd_rn(ax, __fmul_rn(tk, dx));
        float pyf = __fadd_rn(ay, __fmul_rn(tk, dy));
        int px = (int)rintf(pxf); px = px < 0 ? 0 : (px > WW - 1 ? WW - 1 : px);
        int py = (int)rintf(pyf); py = py < 0 ? 0 : (py > HH - 1 ? HH - 1 : py);
        int off = py * WW + px;
        float sc = __fadd_rn(__fmul_rn(ux, pafx[off]), __fmul_rn(uy, pafy[off]));
        if (sc > 0.05f) { npass++; ssum = __fadd_rn(ssum, sc); }
    }
    float ratio = (npass > 0) ? (ssum / (float)npass) : 0.0f;
    float m = fminf(__fsub_rn(256.0f / safe, 1.0f), 0.0f);
    ratio = __fadd_rn(ratio, m);
    bool valid = (ratio > 0.0f) && (npass >= 9) && (kas[i] != 0) && (kbs[j] != 0) && (norm > 0.0f);
    float score = valid ? __fadd_rn(__fadd_rn(ratio, sas[i]), sbs[j]) : 0.0f;

    size_t o = ((size_t)bl * 64 + i) * 64 + j;
    conn[o] = score;
    cvalid[o] = valid ? 1.0f : 0.0f;
}

extern "C" void kernel_launch(void* const* d_in, const int* in_sizes, int n_in,
                              void* d_out, int out_size, void* d_ws, size_t ws_size,
                              hipStream_t stream) {
    const float* hm  = (const float*)d_in[0];
    const float* paf = (const float*)d_in[1];
    float* out = (float*)d_out;

    // Output layout (flat, return order): coords, ss, ks, conn, cvalid
    float* coords = out;                 // 8*19*64*2 = 19456
    float* ss     = out + 19456;         // 8*19*64   = 9728
    float* ks     = out + 29184;         // 8*19*64   = 9728
    float* conn   = out + 38912;         // 8*19*64*64 = 622592
    float* cvalid = out + 661504;        // 8*19*64*64 = 622592

    peaks_kernel<<<8 * 19, 1024, 0, stream>>>(hm, coords, ss, ks);
    limbs_kernel<<<8 * 19 * 16, 256, 0, stream>>>(paf, coords, ss, ks, conn, cvalid);
}

// Round 2
// 314.354 us; speedup vs baseline: 2.4918x; 2.4918x over previous
//
#include <hip/hip_runtime.h>
#include <hip/hip_bf16.h>

#define HH 512
#define WW 512
#define NPIX (HH * WW)
#define KTOP 64
#define NBINS 4096
#define NS 16
#define SLAB_ROWS 32
#define CAPA 1024
#define NMAPS (8 * 19)

static constexpr unsigned MINB = 0x3DCCCCCDu; // bits of 0.1f

__constant__ int KPT_A[19] = {1,1,2,3,5,6,1,8,9,1,11,12,1,0,14,0,15,2,5};
__constant__ int KPT_B[19] = {2,5,3,4,6,7,8,9,10,11,12,13,0,14,16,15,17,16,17};
__constant__ int PAF_X[19] = {12,20,14,16,22,24,0,2,4,6,8,10,28,30,34,32,36,18,26};
__constant__ int PAF_Y[19] = {13,21,15,17,23,25,1,3,5,7,9,11,29,31,35,33,37,19,27};

// Pass 1: per-slab exact top-64 peaks (value desc, idx asc) via bit-histogram.
__global__ __launch_bounds__(256) void peaks_slab_kernel(
    const float* __restrict__ hm_all,
    unsigned* __restrict__ candWs, unsigned* __restrict__ cntWs)
{
    const int slab = blockIdx.x;
    const int map  = blockIdx.y;
    const float* __restrict__ hm = hm_all + (size_t)map * NPIX;
    const int r0 = slab * SLAB_ROWS;
    const int tid = threadIdx.x;

    __shared__ unsigned hist[NBINS];
    __shared__ unsigned candB[CAPA], candI[CAPA];
    __shared__ unsigned chunkSum[256];
    __shared__ unsigned s_cnt, s_thr;
    __shared__ unsigned topB[KTOP], topI[KTOP];

    for (int i = tid; i < NBINS; i += 256) hist[i] = 0u;
    if (tid == 0) s_cnt = 0u;
    if (tid < KTOP) { topB[tid] = 0u; topI[tid] = 0xFFFFFFFFu; }
    __syncthreads();

    // scan 1: histogram of peak values. float4-vectorized, coalesced.
    for (int c = tid; c < SLAB_ROWS * 128; c += 256) {
        int row = r0 + (c >> 7);
        int xc  = (c & 127) << 2;
        const float* rp = hm + row * WW + xc;
        float4 cur = *(const float4*)rp;
        float4 up  = (row > 0)      ? *(const float4*)(rp - WW) : make_float4(0,0,0,0);
        float4 dn  = (row < HH - 1) ? *(const float4*)(rp + WW) : make_float4(0,0,0,0);
        float lf = (xc > 0)      ? rp[-1] : 0.0f;
        float rt = (xc < WW - 4) ? rp[4]  : 0.0f;
        float V[4] = {cur.x, cur.y, cur.z, cur.w};
        float L[4] = {lf, cur.x, cur.y, cur.z};
        float R[4] = {cur.y, cur.z, cur.w, rt};
        float U[4] = {up.x, up.y, up.z, up.w};
        float D[4] = {dn.x, dn.y, dn.z, dn.w};
#pragma unroll
        for (int k = 0; k < 4; k++) {
            float v = V[k];
            if (v < 0.1f) continue;
            // neighbor<0.1 means thresholded neighbor is 0 < v
            bool pk = (R[k] < 0.1f || v > R[k]) && (L[k] < 0.1f || v > L[k]) &&
                      (D[k] < 0.1f || v > D[k]) && (U[k] < 0.1f || v > U[k]);
            if (pk) {
                unsigned b = (__float_as_uint(v) - MINB) >> 13;
                if (b >= NBINS) b = NBINS - 1;
                atomicAdd(&hist[b], 1u);
            }
        }
    }
    __syncthreads();

    {
        unsigned s = 0;
#pragma unroll
        for (int k = 0; k < 16; k++) s += hist[tid * 16 + k];
        chunkSum[tid] = s;
    }
    __syncthreads();
    if (tid == 0) {
        unsigned total = 0;
        for (int k = 0; k < 256; k++) total += chunkSum[k];
        cntWs[map * NS + slab] = total;
        unsigned thr;
        if (total < (unsigned)KTOP) {
            thr = MINB;
        } else {
            unsigned acc = 0; int c = 255;
            for (; c >= 0; c--) {
                if (acc + chunkSum[c] >= (unsigned)KTOP) break;
                acc += chunkSum[c];
            }
            int b = c * 16 + 15;
            unsigned acc2 = acc;
            for (; b >= c * 16; b--) {
                if (acc2 + hist[b] >= (unsigned)KTOP) break;
                acc2 += hist[b];
            }
            thr = MINB + ((unsigned)b << 13);
        }
        s_thr = thr;
    }
    __syncthreads();
    const unsigned thr = s_thr;

    // scan 2: collect candidates >= thr bin (rare: bit pre-check first)
    for (int p = tid; p < SLAB_ROWS * WW; p += 256) {
        int row = r0 + (p >> 9);
        int x = p & 511;
        const float* rp0 = hm + row * WW;
        float v = rp0[x];
        if (v < 0.1f || __float_as_uint(v) < thr) continue;
        float R_ = (x < WW - 1)  ? rp0[x + 1]  : 0.0f;
        float L_ = (x > 0)       ? rp0[x - 1]  : 0.0f;
        float U_ = (row > 0)     ? rp0[x - WW] : 0.0f;
        float D_ = (row < HH-1)  ? rp0[x + WW] : 0.0f;
        bool pk = (R_ < 0.1f || v > R_) && (L_ < 0.1f || v > L_) &&
                  (D_ < 0.1f || v > D_) && (U_ < 0.1f || v > U_);
        if (pk) {
            unsigned pos = atomicAdd(&s_cnt, 1u);
            if (pos < CAPA) { candB[pos] = __float_as_uint(v); candI[pos] = (unsigned)(row * WW + x); }
        }
    }
    __syncthreads();
    int n = (int)(s_cnt < (unsigned)CAPA ? s_cnt : (unsigned)CAPA);

    for (int i = tid; i < n; i += 256) {
        unsigned bi = candB[i], ii = candI[i];
        int rank = 0;
        for (int j = 0; j < n; j++) {
            unsigned bj = candB[j];
            rank += (int)((bj > bi) || (bj == bi && candI[j] < ii));
        }
        if (rank < KTOP) { topB[rank] = bi; topI[rank] = ii; }
    }
    __syncthreads();
    if (tid < KTOP) {
        unsigned* w = &candWs[((size_t)(map * NS + slab) * KTOP + tid) * 2];
        w[0] = topB[tid]; w[1] = topI[tid];
    }
}

// Pass 2: per-map merge of 16x64 candidates -> exact top-64, x-sort, NMS, write.
__global__ __launch_bounds__(1024) void merge_kernel(
    const float* __restrict__ hm_all,
    const unsigned* __restrict__ candWs, const unsigned* __restrict__ cntWs,
    float* __restrict__ coords, float* __restrict__ ss, float* __restrict__ ks)
{
    const int map = blockIdx.x;
    const int tid = threadIdx.x;

    __shared__ unsigned cB[NS * KTOP], cI[NS * KTOP];
    __shared__ int sx[KTOP], sy[KTOP], svalid[KTOP];
    __shared__ float sv[KTOP];
    __shared__ int ox[KTOP], oyv[KTOP], oval[KTOP];
    __shared__ float osc[KTOP];
    __shared__ unsigned s_total;

    {
        const unsigned* w = &candWs[(size_t)map * NS * KTOP * 2];
        cB[tid] = w[tid * 2]; cI[tid] = w[tid * 2 + 1];
    }
    if (tid == 0) {
        unsigned t = 0;
        for (int s = 0; s < NS; s++) t += cntWs[map * NS + s];
        s_total = t;
    }
    if (tid < KTOP) svalid[tid] = 0;
    __syncthreads();
    const unsigned total = s_total;

    {
        unsigned bi = cB[tid], ii = cI[tid];
        if (bi != 0u) {
            int rank = 0;
            for (int j = 0; j < NS * KTOP; j++) {
                unsigned bj = cB[j];
                rank += (int)((bj > bi) || (bj == bi && cI[j] < ii));
            }
            if (rank < KTOP) {
                sx[rank] = (int)(ii & 511u);
                sy[rank] = (int)(ii >> 9);
                sv[rank] = __uint_as_float(bi);
                svalid[rank] = 1;
            }
        }
    }
    __syncthreads();

    // Filler (only when a map has <64 peaks): smallest-index non-peak pixels.
    if (total < (unsigned)KTOP && tid == 0) {
        const float* hm = hm_all + (size_t)map * NPIX;
        auto tval = [&](int y, int x) -> float {
            if ((unsigned)x >= (unsigned)WW || (unsigned)y >= (unsigned)HH) return 0.0f;
            float v = hm[y * WW + x];
            return v < 0.1f ? 0.0f : v;
        };
        int cnt = (int)total;
        for (int p = 0; p < NPIX && cnt < KTOP; p++) {
            float v = hm[p];
            float tv = v < 0.1f ? 0.0f : v;
            int y = p >> 9, x = p & 511;
            bool pk = (tv > tval(y, x + 1)) && (tv > tval(y, x - 1)) &&
                      (tv > tval(y + 1, x)) && (tv > tval(y - 1, x));
            if (!pk) { sx[cnt] = x; sy[cnt] = y; sv[cnt] = tv; svalid[cnt] = 0; cnt++; }
        }
    }
    __syncthreads();

    // Stable sort by (x asc, rank asc); invalid keyed at W+1
    if (tid < KTOP) {
        int xk = svalid[tid] ? sx[tid] : (WW + 1);
        int fpos = 0;
        for (int t = 0; t < KTOP; t++) {
            int xkt = svalid[t] ? sx[t] : (WW + 1);
            fpos += (int)((xkt < xk) || (xkt == xk && t < tid));
        }
        ox[fpos] = sx[tid]; oyv[fpos] = sy[tid]; osc[fpos] = sv[tid]; oval[fpos] = svalid[tid];
    }
    __syncthreads();

    if (tid < KTOP) {
        int x = ox[tid], y = oyv[tid];
        float sc = osc[tid];
        int valid = oval[tid];
        int keep = valid;
        for (int i = 0; i < KTOP; i++) {
            int ki = __shfl(keep, i);
            int xi = __shfl(x, i);
            int yi = __shfl(y, i);
            if (ki && tid > i) {
                int ddx = x - xi, ddy = y - yi;
                if (ddx * ddx + ddy * ddy < 36) keep = 0;
            }
        }
        size_t base = (size_t)map * KTOP + tid;
        coords[base * 2 + 0] = 2.0f * (float)x;
        coords[base * 2 + 1] = 2.0f * (float)y;
        ss[base] = sc;
        ks[base] = keep ? 1.0f : 0.0f;
    }
}

__global__ __launch_bounds__(256) void limbs_kernel(
    const float* __restrict__ paf_all,
    const float* __restrict__ coords, const float* __restrict__ ss, const float* __restrict__ ks,
    float* __restrict__ conn, float* __restrict__ cvalid)
{
    const int blk = blockIdx.x;
    const int q = blk & 15;
    const int bl = blk >> 4;              // b*19 + l
    const int b = bl / 19, l = bl % 19;
    const int tid = threadIdx.x;

    __shared__ float axs[64], ays[64], sas[64];
    __shared__ float bxs[64], bys[64], sbs[64];
    __shared__ int kas[64], kbs[64];

    const int cA = KPT_A[l], cB = KPT_B[l];
    if (tid < 64) {
        size_t ia = (size_t)(b * 19 + cA) * 64 + tid;
        axs[tid] = coords[ia * 2]     * 0.5f;
        ays[tid] = coords[ia * 2 + 1] * 0.5f;
        sas[tid] = ss[ia];
        kas[tid] = ks[ia] > 0.5f;
    } else if (tid < 128) {
        int t = tid - 64;
        size_t ib = (size_t)(b * 19 + cB) * 64 + t;
        bxs[t] = coords[ib * 2]     * 0.5f;
        bys[t] = coords[ib * 2 + 1] * 0.5f;
        sbs[t] = ss[ib];
        kbs[t] = ks[ib] > 0.5f;
    }
    __syncthreads();

    const float* __restrict__ pafx = paf_all + ((size_t)b * 38 + PAF_X[l]) * NPIX;
    const float* __restrict__ pafy = paf_all + ((size_t)b * 38 + PAF_Y[l]) * NPIX;

    const int pair = q * 256 + tid;
    const int i = pair >> 6, j = pair & 63;

    float ax = axs[i], ay = ays[i];
    float bx = bxs[j], by = bys[j];
    float dx = bx - ax, dy = by - ay;
    float norm = sqrtf(__fadd_rn(__fmul_rn(dx, dx), __fmul_rn(dy, dy)));
    float safe = fmaxf(norm, 1e-6f);
    float ux = dx / safe, uy = dy / safe;

    int npass = 0;
    float ssum = 0.0f;
#pragma unroll
    for (int k = 0; k < 10; k++) {
        float tk = (float)k / 9.0f;
        float pxf = __fadd_rn(ax, __fmul_rn(tk, dx));
        float pyf = __fadd_rn(ay, __fmul_rn(tk, dy));
        int px = (int)rintf(pxf); px = px < 0 ? 0 : (px > WW - 1 ? WW - 1 : px);
        int py = (int)rintf(pyf); py = py < 0 ? 0 : (py > HH - 1 ? HH - 1 : py);
        int off = py * WW + px;
        float sc = __fadd_rn(__fmul_rn(ux, pafx[off]), __fmul_rn(uy, pafy[off]));
        if (sc > 0.05f) { npass++; ssum = __fadd_rn(ssum, sc); }
    }
    float ratio = (npass > 0) ? (ssum / (float)npass) : 0.0f;
    float m = fminf(__fsub_rn(256.0f / safe, 1.0f), 0.0f);
    ratio = __fadd_rn(ratio, m);
    bool valid = (ratio > 0.0f) && (npass >= 9) && (kas[i] != 0) && (kbs[j] != 0) && (norm > 0.0f);
    float score = valid ? __fadd_rn(__fadd_rn(ratio, sas[i]), sbs[j]) : 0.0f;

    size_t o = ((size_t)bl * 64 + i) * 64 + j;
    conn[o] = score;
    cvalid[o] = valid ? 1.0f : 0.0f;
}

extern "C" void kernel_launch(void* const* d_in, const int* in_sizes, int n_in,
                              void* d_out, int out_size, void* d_ws, size_t ws_size,
                              hipStream_t stream) {
    const float* hm  = (const float*)d_in[0];
    const float* paf = (const float*)d_in[1];
    float* out = (float*)d_out;

    // Output layout (flat, return order): coords, ss, ks, conn, cvalid
    float* coords = out;                 // 8*19*64*2 = 19456
    float* ss     = out + 19456;         // 8*19*64   = 9728
    float* ks     = out + 29184;         // 8*19*64   = 9728
    float* conn   = out + 38912;         // 8*19*64*64 = 622592
    float* cvalid = out + 661504;        // 8*19*64*64 = 622592

    // Scratch lives inside the conn region (fully overwritten by limbs_kernel):
    // candWs: 152*16*64*2 u32 = 311296 u32; cntWs: 152*16 u32
    unsigned* candWs = (unsigned*)(out + 38912);
    unsigned* cntWs  = (unsigned*)(out + 38912 + 311296);

    dim3 gA(NS, NMAPS);
    peaks_slab_kernel<<<gA, 256, 0, stream>>>(hm, candWs, cntWs);
    merge_kernel<<<NMAPS, 1024, 0, stream>>>(hm, candWs, cntWs, coords, ss, ks);
    limbs_kernel<<<NMAPS * 16, 256, 0, stream>>>(paf, coords, ss, ks, conn, cvalid);
}

// Round 3
// 237.772 us; speedup vs baseline: 3.2944x; 1.3221x over previous
//
#include <hip/hip_runtime.h>
#include <hip/hip_bf16.h>

#define HH 512
#define WW 512
#define NPIX (HH * WW)
#define KTOP 64
#define NBINS 4096
#define NS 16
#define SLAB_ROWS 32
#define CAPA 1024
#define NMAPS (8 * 19)

static constexpr unsigned MINB = 0x3DCCCCCDu; // bits of 0.1f

__constant__ int KPT_A[19] = {1,1,2,3,5,6,1,8,9,1,11,12,1,0,14,0,15,2,5};
__constant__ int KPT_B[19] = {2,5,3,4,6,7,8,9,10,11,12,13,0,14,16,15,17,16,17};
__constant__ int PAF_X[19] = {12,20,14,16,22,24,0,2,4,6,8,10,28,30,34,32,36,18,26};
__constant__ int PAF_Y[19] = {13,21,15,17,23,25,1,3,5,7,9,11,29,31,35,33,37,19,27};

// key = (value bits << 32) | ~idx  -> rank by key DESC == (value desc, idx asc)
__device__ __forceinline__ unsigned long long mkkey(unsigned bits, unsigned idx) {
    return ((unsigned long long)bits << 32) | (unsigned long long)(~idx);
}

// Pass 1: per-slab exact top-64 peaks via bit-histogram.
__global__ __launch_bounds__(256) void peaks_slab_kernel(
    const float* __restrict__ hm_all,
    unsigned long long* __restrict__ candWs, unsigned* __restrict__ cntWs)
{
    const int slab = blockIdx.x;
    const int map  = blockIdx.y;
    const float* __restrict__ hm = hm_all + (size_t)map * NPIX;
    const int r0 = slab * SLAB_ROWS;
    const int tid = threadIdx.x;

    __shared__ unsigned hist[NBINS];
    __shared__ unsigned long long cK[CAPA];
    __shared__ unsigned chunkSum[256];
    __shared__ unsigned s_cnt, s_thr;
    __shared__ unsigned long long topK[KTOP];

    for (int i = tid; i < NBINS; i += 256) hist[i] = 0u;
    if (tid == 0) s_cnt = 0u;
    if (tid < KTOP) topK[tid] = 0ull;
    __syncthreads();

    // scan 1: histogram of peak values. float4-vectorized, coalesced.
    for (int c = tid; c < SLAB_ROWS * 128; c += 256) {
        int row = r0 + (c >> 7);
        int xc  = (c & 127) << 2;
        const float* rp = hm + row * WW + xc;
        float4 cur = *(const float4*)rp;
        float4 up  = (row > 0)      ? *(const float4*)(rp - WW) : make_float4(0,0,0,0);
        float4 dn  = (row < HH - 1) ? *(const float4*)(rp + WW) : make_float4(0,0,0,0);
        float lf = (xc > 0)      ? rp[-1] : 0.0f;
        float rt = (xc < WW - 4) ? rp[4]  : 0.0f;
        float V[4] = {cur.x, cur.y, cur.z, cur.w};
        float L[4] = {lf, cur.x, cur.y, cur.z};
        float R[4] = {cur.y, cur.z, cur.w, rt};
        float U[4] = {up.x, up.y, up.z, up.w};
        float D[4] = {dn.x, dn.y, dn.z, dn.w};
#pragma unroll
        for (int k = 0; k < 4; k++) {
            float v = V[k];
            if (v < 0.1f) continue;
            bool pk = (R[k] < 0.1f || v > R[k]) && (L[k] < 0.1f || v > L[k]) &&
                      (D[k] < 0.1f || v > D[k]) && (U[k] < 0.1f || v > U[k]);
            if (pk) {
                unsigned b = (__float_as_uint(v) - MINB) >> 13;
                if (b >= NBINS) b = NBINS - 1;
                atomicAdd(&hist[b], 1u);
            }
        }
    }
    __syncthreads();

    {
        unsigned s = 0;
#pragma unroll
        for (int k = 0; k < 16; k++) s += hist[tid * 16 + k];
        chunkSum[tid] = s;
    }
    __syncthreads();
    if (tid == 0) {
        unsigned total = 0;
        for (int k = 0; k < 256; k++) total += chunkSum[k];
        cntWs[map * NS + slab] = total;
        unsigned thr;
        if (total < (unsigned)KTOP) {
            thr = MINB;
        } else {
            unsigned acc = 0; int c = 255;
            for (; c >= 0; c--) {
                if (acc + chunkSum[c] >= (unsigned)KTOP) break;
                acc += chunkSum[c];
            }
            int b = c * 16 + 15;
            unsigned acc2 = acc;
            for (; b >= c * 16; b--) {
                if (acc2 + hist[b] >= (unsigned)KTOP) break;
                acc2 += hist[b];
            }
            thr = MINB + ((unsigned)b << 13);
        }
        s_thr = thr;
    }
    __syncthreads();
    const unsigned thr = s_thr;

    // scan 2: collect candidates >= thr bin
    for (int p = tid; p < SLAB_ROWS * WW; p += 256) {
        int row = r0 + (p >> 9);
        int x = p & 511;
        const float* rp0 = hm + row * WW;
        float v = rp0[x];
        if (v < 0.1f || __float_as_uint(v) < thr) continue;
        float R_ = (x < WW - 1)  ? rp0[x + 1]  : 0.0f;
        float L_ = (x > 0)       ? rp0[x - 1]  : 0.0f;
        float U_ = (row > 0)     ? rp0[x - WW] : 0.0f;
        float D_ = (row < HH-1)  ? rp0[x + WW] : 0.0f;
        bool pk = (R_ < 0.1f || v > R_) && (L_ < 0.1f || v > L_) &&
                  (D_ < 0.1f || v > D_) && (U_ < 0.1f || v > U_);
        if (pk) {
            unsigned pos = atomicAdd(&s_cnt, 1u);
            if (pos < CAPA) cK[pos] = mkkey(__float_as_uint(v), (unsigned)(row * WW + x));
        }
    }
    __syncthreads();
    int n = (int)(s_cnt < (unsigned)CAPA ? s_cnt : (unsigned)CAPA);

    for (int i = tid; i < n; i += 256) {
        unsigned long long ki = cK[i];
        int rank = 0;
        for (int j = 0; j < n; j++) rank += (int)(cK[j] > ki);
        if (rank < KTOP) topK[rank] = ki;
    }
    __syncthreads();
    if (tid < KTOP)
        candWs[(size_t)(map * NS + slab) * KTOP + tid] = topK[tid];
}

// Pass 2: per-map merge of 16x64 candidates -> exact top-64, x-sort, NMS, write.
__global__ __launch_bounds__(1024) void merge_kernel(
    const float* __restrict__ hm_all,
    const unsigned long long* __restrict__ candWs, const unsigned* __restrict__ cntWs,
    float* __restrict__ coords, float* __restrict__ ss, float* __restrict__ ks)
{
    const int map = blockIdx.x;
    const int tid = threadIdx.x;

    __shared__ unsigned long long cK[NS * KTOP];
    __shared__ int sx[KTOP], sy[KTOP], svalid[KTOP];
    __shared__ float sv[KTOP];
    __shared__ int ox[KTOP], oyv[KTOP], oval[KTOP];
    __shared__ float osc[KTOP];
    __shared__ unsigned s_total;

    cK[tid] = candWs[(size_t)map * NS * KTOP + tid];
    if (tid == 0) {
        unsigned t = 0;
        for (int s = 0; s < NS; s++) t += cntWs[map * NS + s];
        s_total = t;
    }
    if (tid < KTOP) svalid[tid] = 0;
    __syncthreads();
    const unsigned total = s_total;

    {
        unsigned long long ki = cK[tid];
        if (ki != 0ull) {
            int rank = 0;
            for (int j = 0; j < NS * KTOP; j++) rank += (int)(cK[j] > ki);
            if (rank < KTOP) {
                unsigned ii = ~(unsigned)ki;
                sx[rank] = (int)(ii & 511u);
                sy[rank] = (int)(ii >> 9);
                sv[rank] = __uint_as_float((unsigned)(ki >> 32));
                svalid[rank] = 1;
            }
        }
    }
    __syncthreads();

    // Filler (only when a map has <64 peaks): smallest-index non-peak pixels.
    if (total < (unsigned)KTOP && tid == 0) {
        const float* hm = hm_all + (size_t)map * NPIX;
        auto tval = [&](int y, int x) -> float {
            if ((unsigned)x >= (unsigned)WW || (unsigned)y >= (unsigned)HH) return 0.0f;
            float v = hm[y * WW + x];
            return v < 0.1f ? 0.0f : v;
        };
        int cnt = (int)total;
        for (int p = 0; p < NPIX && cnt < KTOP; p++) {
            float v = hm[p];
            float tv = v < 0.1f ? 0.0f : v;
            int y = p >> 9, x = p & 511;
            bool pk = (tv > tval(y, x + 1)) && (tv > tval(y, x - 1)) &&
                      (tv > tval(y + 1, x)) && (tv > tval(y - 1, x));
            if (!pk) { sx[cnt] = x; sy[cnt] = y; sv[cnt] = tv; svalid[cnt] = 0; cnt++; }
        }
    }
    __syncthreads();

    // Stable sort by (x asc, rank asc); invalid keyed at W+1
    if (tid < KTOP) {
        int xk = svalid[tid] ? sx[tid] : (WW + 1);
        int fpos = 0;
        for (int t = 0; t < KTOP; t++) {
            int xkt = svalid[t] ? sx[t] : (WW + 1);
            fpos += (int)((xkt < xk) || (xkt == xk && t < tid));
        }
        ox[fpos] = sx[tid]; oyv[fpos] = sy[tid]; osc[fpos] = sv[tid]; oval[fpos] = svalid[tid];
    }
    __syncthreads();

    if (tid < KTOP) {
        int x = ox[tid], y = oyv[tid];
        float sc = osc[tid];
        int valid = oval[tid];
        int keep = valid;
        for (int i = 0; i < KTOP; i++) {
            int ki = __shfl(keep, i);
            int xi = __shfl(x, i);
            int yi = __shfl(y, i);
            if (ki && tid > i) {
                int ddx = x - xi, ddy = y - yi;
                if (ddx * ddx + ddy * ddy < 36) keep = 0;
            }
        }
        size_t base = (size_t)map * KTOP + tid;
        coords[base * 2 + 0] = 2.0f * (float)x;
        coords[base * 2 + 1] = 2.0f * (float)y;
        ss[base] = sc;
        ks[base] = keep ? 1.0f : 0.0f;
    }
}

__global__ __launch_bounds__(256) void limbs_kernel(
    const float* __restrict__ paf_all,
    const float* __restrict__ coords, const float* __restrict__ ss, const float* __restrict__ ks,
    float* __restrict__ conn, float* __restrict__ cvalid)
{
    // XCD-locality swizzle: round-robin dispatch sends block B to XCD B%8.
    // Give each XCD 19 whole limbs so its 2 MB/limb PAF working set stays in
    // its private L2 (16 q-blocks of one (b,l) co-resident on one XCD).
    const int B = blockIdx.x;
    const int xcd = B & 7;
    const int seq = B >> 3;               // 0..303
    const int bl  = xcd * 19 + (seq >> 4);// b*19 + l
    const int q   = seq & 15;
    const int b = bl / 19, l = bl % 19;
    const int tid = threadIdx.x;

    __shared__ float axs[64], ays[64], sas[64];
    __shared__ float bxs[64], bys[64], sbs[64];
    __shared__ int kas[64], kbs[64];

    const int cA = KPT_A[l], cB = KPT_B[l];
    if (tid < 64) {
        size_t ia = (size_t)(b * 19 + cA) * 64 + tid;
        axs[tid] = coords[ia * 2]     * 0.5f;
        ays[tid] = coords[ia * 2 + 1] * 0.5f;
        sas[tid] = ss[ia];
        kas[tid] = ks[ia] > 0.5f;
    } else if (tid < 128) {
        int t = tid - 64;
        size_t ib = (size_t)(b * 19 + cB) * 64 + t;
        bxs[t] = coords[ib * 2]     * 0.5f;
        bys[t] = coords[ib * 2 + 1] * 0.5f;
        sbs[t] = ss[ib];
        kbs[t] = ks[ib] > 0.5f;
    }
    __syncthreads();

    const float* __restrict__ pafx = paf_all + ((size_t)b * 38 + PAF_X[l]) * NPIX;
    const float* __restrict__ pafy = paf_all + ((size_t)b * 38 + PAF_Y[l]) * NPIX;

    const int pair = q * 256 + tid;
    const int i = pair >> 6, j = pair & 63;

    float score = 0.0f, cval = 0.0f;
    if (kas[i] && kbs[j]) {
        float ax = axs[i], ay = ays[i];
        float bx = bxs[j], by = bys[j];
        float dx = bx - ax, dy = by - ay;
        float norm = sqrtf(__fadd_rn(__fmul_rn(dx, dx), __fmul_rn(dy, dy)));
        float safe = fmaxf(norm, 1e-6f);
        float ux = dx / safe, uy = dy / safe;

        int npass = 0;
        float ssum = 0.0f;
#pragma unroll
        for (int k = 0; k < 10; k++) {
            float tk = (float)k / 9.0f;
            float pxf = __fadd_rn(ax, __fmul_rn(tk, dx));
            float pyf = __fadd_rn(ay, __fmul_rn(tk, dy));
            int px = (int)rintf(pxf); px = px < 0 ? 0 : (px > WW - 1 ? WW - 1 : px);
            int py = (int)rintf(pyf); py = py < 0 ? 0 : (py > HH - 1 ? HH - 1 : py);
            int off = py * WW + px;
            float sc = __fadd_rn(__fmul_rn(ux, pafx[off]), __fmul_rn(uy, pafy[off]));
            if (sc > 0.05f) { npass++; ssum = __fadd_rn(ssum, sc); }
        }
        float ratio = (npass > 0) ? (ssum / (float)npass) : 0.0f;
        float m = fminf(__fsub_rn(256.0f / safe, 1.0f), 0.0f);
        ratio = __fadd_rn(ratio, m);
        bool valid = (ratio > 0.0f) && (npass >= 9) && (norm > 0.0f);
        if (valid) {
            score = __fadd_rn(__fadd_rn(ratio, sas[i]), sbs[j]);
            cval = 1.0f;
        }
    }

    size_t o = ((size_t)bl * 64 + i) * 64 + j;
    conn[o] = score;
    cvalid[o] = cval;
}

extern "C" void kernel_launch(void* const* d_in, const int* in_sizes, int n_in,
                              void* d_out, int out_size, void* d_ws, size_t ws_size,
                              hipStream_t stream) {
    const float* hm  = (const float*)d_in[0];
    const float* paf = (const float*)d_in[1];
    float* out = (float*)d_out;

    // Output layout (flat, return order): coords, ss, ks, conn, cvalid
    float* coords = out;                 // 8*19*64*2 = 19456
    float* ss     = out + 19456;         // 8*19*64   = 9728
    float* ks     = out + 29184;         // 8*19*64   = 9728
    float* conn   = out + 38912;         // 8*19*64*64 = 622592
    float* cvalid = out + 661504;        // 8*19*64*64 = 622592

    // Scratch inside the conn region (fully overwritten by limbs_kernel):
    // candWs: 152*16*64 u64 = 311296 u32; cntWs: 152*16 u32
    unsigned long long* candWs = (unsigned long long*)(out + 38912);
    unsigned* cntWs = (unsigned*)(out + 38912 + 311296);

    dim3 gA(NS, NMAPS);
    peaks_slab_kernel<<<gA, 256, 0, stream>>>(hm, candWs, cntWs);
    merge_kernel<<<NMAPS, 1024, 0, stream>>>(hm, candWs, cntWs, coords, ss, ks);
    limbs_kernel<<<NMAPS * 16, 256, 0, stream>>>(paf, coords, ss, ks, conn, cvalid);
}

// Round 4
// 186.731 us; speedup vs baseline: 4.1949x; 1.2733x over previous
//
#include <hip/hip_runtime.h>
#include <hip/hip_bf16.h>

#define HH 512
#define WW 512
#define NPIX (HH * WW)
#define KTOP 64
#define NBINS2 2048
#define NS 16
#define SLAB_ROWS 32
#define CAP2 4096
#define SELCAP 512
#define NMAPS (8 * 19)

static constexpr unsigned MINB = 0x3DCCCCCDu; // bits of 0.1f

__constant__ int KPT_A[19] = {1,1,2,3,5,6,1,8,9,1,11,12,1,0,14,0,15,2,5};
__constant__ int KPT_B[19] = {2,5,3,4,6,7,8,9,10,11,12,13,0,14,16,15,17,16,17};
__constant__ int PAF_X[19] = {12,20,14,16,22,24,0,2,4,6,8,10,28,30,34,32,36,18,26};
__constant__ int PAF_Y[19] = {13,21,15,17,23,25,1,3,5,7,9,11,29,31,35,33,37,19,27};

// key = (value bits << 32) | ~idx  -> rank by key DESC == (value desc, idx asc)
__device__ __forceinline__ unsigned long long mkkey(unsigned bits, unsigned idx) {
    return ((unsigned long long)bits << 32) | (unsigned long long)(~idx);
}

// Pass 1: per-slab exact top-64 peaks. Single global scan: histogram AND
// full candidate capture in LDS; selection is then LDS-only.
__global__ __launch_bounds__(256) void peaks_slab_kernel(
    const float* __restrict__ hm_all,
    unsigned long long* __restrict__ candWs, unsigned* __restrict__ cntWs)
{
    const int slab = blockIdx.x;
    const int map  = blockIdx.y;
    const float* __restrict__ hm = hm_all + (size_t)map * NPIX;
    const int r0 = slab * SLAB_ROWS;
    const int tid = threadIdx.x;

    __shared__ unsigned hist[NBINS2];
    __shared__ unsigned long long allK[CAP2];
    __shared__ unsigned long long selK[SELCAP];
    __shared__ unsigned chunkSum[256];
    __shared__ unsigned s_cnt, s_sel, s_thr;
    __shared__ unsigned long long topK[KTOP];

    for (int i = tid; i < NBINS2; i += 256) hist[i] = 0u;
    if (tid == 0) { s_cnt = 0u; s_sel = 0u; }
    if (tid < KTOP) topK[tid] = 0ull;
    __syncthreads();

    // scan: float4-vectorized, coalesced. Histogram + capture every peak key.
    for (int c = tid; c < SLAB_ROWS * 128; c += 256) {
        int row = r0 + (c >> 7);
        int xc  = (c & 127) << 2;
        const float* rp = hm + row * WW + xc;
        float4 cur = *(const float4*)rp;
        float4 up  = (row > 0)      ? *(const float4*)(rp - WW) : make_float4(0,0,0,0);
        float4 dn  = (row < HH - 1) ? *(const float4*)(rp + WW) : make_float4(0,0,0,0);
        float lf = (xc > 0)      ? rp[-1] : 0.0f;
        float rt = (xc < WW - 4) ? rp[4]  : 0.0f;
        float V[4] = {cur.x, cur.y, cur.z, cur.w};
        float L[4] = {lf, cur.x, cur.y, cur.z};
        float R[4] = {cur.y, cur.z, cur.w, rt};
        float U[4] = {up.x, up.y, up.z, up.w};
        float D[4] = {dn.x, dn.y, dn.z, dn.w};
#pragma unroll
        for (int k = 0; k < 4; k++) {
            float v = V[k];
            if (v < 0.1f) continue;
            // neighbor<0.1 -> thresholded neighbor is 0 < v
            bool pk = (R[k] < 0.1f || v > R[k]) && (L[k] < 0.1f || v > L[k]) &&
                      (D[k] < 0.1f || v > D[k]) && (U[k] < 0.1f || v > U[k]);
            if (pk) {
                unsigned bits = __float_as_uint(v);
                unsigned b = (bits - MINB) >> 14;
                if (b >= NBINS2) b = NBINS2 - 1;
                atomicAdd(&hist[b], 1u);
                unsigned pos = atomicAdd(&s_cnt, 1u);
                if (pos < CAP2) allK[pos] = mkkey(bits, (unsigned)(row * WW + xc + k));
            }
        }
    }
    __syncthreads();

    {
        unsigned s = 0;
#pragma unroll
        for (int k = 0; k < 8; k++) s += hist[tid * 8 + k];
        chunkSum[tid] = s;
    }
    __syncthreads();
    if (tid == 0) {
        unsigned total = 0;
        for (int k = 0; k < 256; k++) total += chunkSum[k];
        cntWs[map * NS + slab] = total;
        unsigned thr;
        if (total < (unsigned)KTOP) {
            thr = MINB;
        } else {
            unsigned acc = 0; int c = 255;
            for (; c >= 0; c--) {
                if (acc + chunkSum[c] >= (unsigned)KTOP) break;
                acc += chunkSum[c];
            }
            int b = c * 8 + 7;
            unsigned acc2 = acc;
            for (; b >= c * 8; b--) {
                if (acc2 + hist[b] >= (unsigned)KTOP) break;
                acc2 += hist[b];
            }
            thr = MINB + ((unsigned)b << 14);
        }
        s_thr = thr;
    }
    __syncthreads();
    const unsigned thr = s_thr;
    const unsigned stored = s_cnt;

    if (stored <= (unsigned)CAP2) {
        // LDS-only compaction of candidates >= thr bin
        for (unsigned i = tid; i < stored; i += 256) {
            unsigned long long k = allK[i];
            if ((unsigned)(k >> 32) >= thr) {
                unsigned p = atomicAdd(&s_sel, 1u);
                if (p < SELCAP) selK[p] = k;
            }
        }
    } else {
        // fallback (capture overflow — not expected for this data): re-scan global
        for (int p = tid; p < SLAB_ROWS * WW; p += 256) {
            int row = r0 + (p >> 9);
            int x = p & 511;
            const float* rp0 = hm + row * WW;
            float v = rp0[x];
            if (v < 0.1f || __float_as_uint(v) < thr) continue;
            float R_ = (x < WW - 1)  ? rp0[x + 1]  : 0.0f;
            float L_ = (x > 0)       ? rp0[x - 1]  : 0.0f;
            float U_ = (row > 0)     ? rp0[x - WW] : 0.0f;
            float D_ = (row < HH-1)  ? rp0[x + WW] : 0.0f;
            bool pk = (R_ < 0.1f || v > R_) && (L_ < 0.1f || v > L_) &&
                      (D_ < 0.1f || v > D_) && (U_ < 0.1f || v > U_);
            if (pk) {
                unsigned p2 = atomicAdd(&s_sel, 1u);
                if (p2 < SELCAP) selK[p2] = mkkey(__float_as_uint(v), (unsigned)(row * WW + x));
            }
        }
    }
    __syncthreads();
    int m = (int)(s_sel < (unsigned)SELCAP ? s_sel : (unsigned)SELCAP);

    // exact rank among selected (all non-selected keys are strictly smaller)
    for (int i = tid; i < m; i += 256) {
        unsigned long long ki = selK[i];
        int rank = 0;
        for (int j = 0; j < m; j++) rank += (int)(selK[j] > ki);
        if (rank < KTOP) topK[rank] = ki;
    }
    __syncthreads();
    if (tid < KTOP)
        candWs[(size_t)(map * NS + slab) * KTOP + tid] = topK[tid];
}

// Pass 2: per-map merge of 16x64 candidates -> exact top-64, x-sort, NMS, write.
__global__ __launch_bounds__(1024) void merge_kernel(
    const float* __restrict__ hm_all,
    const unsigned long long* __restrict__ candWs, const unsigned* __restrict__ cntWs,
    float* __restrict__ coords, float* __restrict__ ss, float* __restrict__ ks)
{
    const int map = blockIdx.x;
    const int tid = threadIdx.x;

    __shared__ unsigned long long cK[NS * KTOP];
    __shared__ int sx[KTOP], sy[KTOP], svalid[KTOP];
    __shared__ float sv[KTOP];
    __shared__ int ox[KTOP], oyv[KTOP], oval[KTOP];
    __shared__ float osc[KTOP];
    __shared__ unsigned s_total;

    cK[tid] = candWs[(size_t)map * NS * KTOP + tid];
    if (tid == 0) {
        unsigned t = 0;
        for (int s = 0; s < NS; s++) t += cntWs[map * NS + s];
        s_total = t;
    }
    if (tid < KTOP) svalid[tid] = 0;
    __syncthreads();
    const unsigned total = s_total;

    {
        unsigned long long ki = cK[tid];
        if (ki != 0ull) {
            int rank = 0;
            for (int j = 0; j < NS * KTOP; j++) rank += (int)(cK[j] > ki);
            if (rank < KTOP) {
                unsigned ii = ~(unsigned)ki;
                sx[rank] = (int)(ii & 511u);
                sy[rank] = (int)(ii >> 9);
                sv[rank] = __uint_as_float((unsigned)(ki >> 32));
                svalid[rank] = 1;
            }
        }
    }
    __syncthreads();

    // Filler (only when a map has <64 peaks): smallest-index non-peak pixels.
    if (total < (unsigned)KTOP && tid == 0) {
        const float* hm = hm_all + (size_t)map * NPIX;
        auto tval = [&](int y, int x) -> float {
            if ((unsigned)x >= (unsigned)WW || (unsigned)y >= (unsigned)HH) return 0.0f;
            float v = hm[y * WW + x];
            return v < 0.1f ? 0.0f : v;
        };
        int cnt = (int)total;
        for (int p = 0; p < NPIX && cnt < KTOP; p++) {
            float v = hm[p];
            float tv = v < 0.1f ? 0.0f : v;
            int y = p >> 9, x = p & 511;
            bool pk = (tv > tval(y, x + 1)) && (tv > tval(y, x - 1)) &&
                      (tv > tval(y + 1, x)) && (tv > tval(y - 1, x));
            if (!pk) { sx[cnt] = x; sy[cnt] = y; sv[cnt] = tv; svalid[cnt] = 0; cnt++; }
        }
    }
    __syncthreads();

    // Stable sort by (x asc, rank asc); invalid keyed at W+1
    if (tid < KTOP) {
        int xk = svalid[tid] ? sx[tid] : (WW + 1);
        int fpos = 0;
        for (int t = 0; t < KTOP; t++) {
            int xkt = svalid[t] ? sx[t] : (WW + 1);
            fpos += (int)((xkt < xk) || (xkt == xk && t < tid));
        }
        ox[fpos] = sx[tid]; oyv[fpos] = sy[tid]; osc[fpos] = sv[tid]; oval[fpos] = svalid[tid];
    }
    __syncthreads();

    if (tid < KTOP) {
        int x = ox[tid], y = oyv[tid];
        float sc = osc[tid];
        int valid = oval[tid];
        int keep = valid;
        for (int i = 0; i < KTOP; i++) {
            int ki = __shfl(keep, i);
            int xi = __shfl(x, i);
            int yi = __shfl(y, i);
            if (ki && tid > i) {
                int ddx = x - xi, ddy = y - yi;
                if (ddx * ddx + ddy * ddy < 36) keep = 0;
            }
        }
        size_t base = (size_t)map * KTOP + tid;
        coords[base * 2 + 0] = 2.0f * (float)x;
        coords[base * 2 + 1] = 2.0f * (float)y;
        ss[base] = sc;
        ks[base] = keep ? 1.0f : 0.0f;
    }
}

__global__ __launch_bounds__(256) void limbs_kernel(
    const float* __restrict__ paf_all,
    const float* __restrict__ coords, const float* __restrict__ ss, const float* __restrict__ ks,
    float* __restrict__ conn, float* __restrict__ cvalid)
{
    // XCD-locality swizzle: round-robin dispatch sends block B to XCD B%8.
    // Each XCD gets 19 whole limbs (one batch) so the per-limb 2 MB PAF
    // working set stays in its private L2.
    const int B = blockIdx.x;
    const int xcd = B & 7;
    const int seq = B >> 3;               // 0..303
    const int bl  = xcd * 19 + (seq >> 4);// b*19 + l
    const int q   = seq & 15;
    const int b = bl / 19, l = bl % 19;
    const int tid = threadIdx.x;

    __shared__ float axs[64], ays[64], sas[64];
    __shared__ float bxs[64], bys[64], sbs[64];
    __shared__ int kas[64], kbs[64];

    const int cA = KPT_A[l], cB = KPT_B[l];
    if (tid < 64) {
        size_t ia = (size_t)(b * 19 + cA) * 64 + tid;
        axs[tid] = coords[ia * 2]     * 0.5f;
        ays[tid] = coords[ia * 2 + 1] * 0.5f;
        sas[tid] = ss[ia];
        kas[tid] = ks[ia] > 0.5f;
    } else if (tid < 128) {
        int t = tid - 64;
        size_t ib = (size_t)(b * 19 + cB) * 64 + t;
        bxs[t] = coords[ib * 2]     * 0.5f;
        bys[t] = coords[ib * 2 + 1] * 0.5f;
        sbs[t] = ss[ib];
        kbs[t] = ks[ib] > 0.5f;
    }
    __syncthreads();

    const float* __restrict__ pafx = paf_all + ((size_t)b * 38 + PAF_X[l]) * NPIX;
    const float* __restrict__ pafy = paf_all + ((size_t)b * 38 + PAF_Y[l]) * NPIX;

    const int pair = q * 256 + tid;
    const int i = pair >> 6, j = pair & 63;

    float score = 0.0f, cval = 0.0f;
    if (kas[i] && kbs[j]) {
        float ax = axs[i], ay = ays[i];
        float bx = bxs[j], by = bys[j];
        float dx = bx - ax, dy = by - ay;
        float norm = sqrtf(__fadd_rn(__fmul_rn(dx, dx), __fmul_rn(dy, dy)));
        float safe = fmaxf(norm, 1e-6f);
        float ux = dx / safe, uy = dy / safe;

        int npass = 0, fails = 0;
        float ssum = 0.0f;
        // Early exit after 2nd failing sample: npass>=9 then impossible, and
        // every output is exactly 0 in that case — bit-identical shortcut.
#define SAMPLE(TK)                                                              \
        {                                                                       \
            float pxf = __fadd_rn(ax, __fmul_rn((TK), dx));                     \
            float pyf = __fadd_rn(ay, __fmul_rn((TK), dy));                     \
            int px = (int)rintf(pxf); px = px < 0 ? 0 : (px > WW - 1 ? WW - 1 : px); \
            int py = (int)rintf(pyf); py = py < 0 ? 0 : (py > HH - 1 ? HH - 1 : py); \
            int off = py * WW + px;                                             \
            float sc = __fadd_rn(__fmul_rn(ux, pafx[off]), __fmul_rn(uy, pafy[off])); \
            if (sc > 0.05f) { npass++; ssum = __fadd_rn(ssum, sc); }            \
            else if (++fails == 2) goto reject;                                 \
        }
        SAMPLE(0.0f)
        SAMPLE(1.0f / 9.0f)
        SAMPLE(2.0f / 9.0f)
        SAMPLE(3.0f / 9.0f)
        SAMPLE(4.0f / 9.0f)
        SAMPLE(5.0f / 9.0f)
        SAMPLE(6.0f / 9.0f)
        SAMPLE(7.0f / 9.0f)
        SAMPLE(8.0f / 9.0f)
        SAMPLE(1.0f)
#undef SAMPLE
        {
            float ratio = (npass > 0) ? (ssum / (float)npass) : 0.0f;
            float mpen = fminf(__fsub_rn(256.0f / safe, 1.0f), 0.0f);
            ratio = __fadd_rn(ratio, mpen);
            bool valid = (ratio > 0.0f) && (npass >= 9) && (norm > 0.0f);
            if (valid) {
                score = __fadd_rn(__fadd_rn(ratio, sas[i]), sbs[j]);
                cval = 1.0f;
            }
        }
reject: ;
    }

    size_t o = ((size_t)bl * 64 + i) * 64 + j;
    conn[o] = score;
    cvalid[o] = cval;
}

extern "C" void kernel_launch(void* const* d_in, const int* in_sizes, int n_in,
                              void* d_out, int out_size, void* d_ws, size_t ws_size,
                              hipStream_t stream) {
    const float* hm  = (const float*)d_in[0];
    const float* paf = (const float*)d_in[1];
    float* out = (float*)d_out;

    // Output layout (flat, return order): coords, ss, ks, conn, cvalid
    float* coords = out;                 // 8*19*64*2 = 19456
    float* ss     = out + 19456;         // 8*19*64   = 9728
    float* ks     = out + 29184;         // 8*19*64   = 9728
    float* conn   = out + 38912;         // 8*19*64*64 = 622592
    float* cvalid = out + 661504;        // 8*19*64*64 = 622592

    // Scratch inside the conn region (fully overwritten by limbs_kernel):
    // candWs: 152*16*64 u64 = 311296 u32; cntWs: 152*16 u32
    unsigned long long* candWs = (unsigned long long*)(out + 38912);
    unsigned* cntWs = (unsigned*)(out + 38912 + 311296);

    dim3 gA(NS, NMAPS);
    peaks_slab_kernel<<<gA, 256, 0, stream>>>(hm, candWs, cntWs);
    merge_kernel<<<NMAPS, 1024, 0, stream>>>(hm, candWs, cntWs, coords, ss, ks);
    limbs_kernel<<<NMAPS * 16, 256, 0, stream>>>(paf, coords, ss, ks, conn, cvalid);
}